// Round 3
// baseline (269.895 us; speedup 1.0000x reference)
//
#include <hip/hip_runtime.h>
#include <hip/hip_bf16.h>

#define NN 512
#define NI 64
#define NJ 16
#define DD 256
#define HI 64
#define HO 64
#define NT 16   // n-rows per fused block

typedef unsigned int  u32;
typedef unsigned short u16;

typedef __attribute__((ext_vector_type(8))) short bf16x8;
typedef __attribute__((ext_vector_type(4))) float f32x4;

__device__ __forceinline__ float gelu_exact(float x){
    return 0.5f * x * (1.0f + erff(x * 0.7071067811865476f));
}
__device__ __forceinline__ float sigm(float x){
    return 1.0f / (1.0f + __expf(-x));
}
__device__ __forceinline__ float us2f(u16 u){
    union { u32 ui; float f; } cv; cv.ui = ((u32)u) << 16; return cv.f;
}
__device__ __forceinline__ float bflo(u32 x){
    union { u32 u; float f; } c; c.u = x << 16; return c.f;
}
__device__ __forceinline__ float bfhi(u32 x){
    union { u32 u; float f; } c; c.u = x & 0xffff0000u; return c.f;
}
__device__ __forceinline__ u16 f2us(float f){
    union { float f; u32 u; } cv; cv.f = f;
    u32 r = cv.u + 0x7FFFu + ((cv.u >> 16) & 1u);   // RNE
    return (u16)(r >> 16);
}
__device__ __forceinline__ float dot8(uint4 q, const float* v){
    return bflo(q.x) * v[0] + bfhi(q.x) * v[1]
         + bflo(q.y) * v[2] + bfhi(q.y) * v[3]
         + bflo(q.z) * v[4] + bfhi(q.z) * v[5]
         + bflo(q.w) * v[6] + bfhi(q.w) * v[7];
}

// ------------- prep: small weights -> bf16 (fe1W transposed) -------------
__global__ __launch_bounds__(256) void k_prep_small(
    const float* __restrict__ fn1W, const float* __restrict__ fe2W,
    const float* __restrict__ fn2W, const float* __restrict__ fe1W,
    u16* __restrict__ fn1wb, u16* __restrict__ wAb,
    u16* __restrict__ wBb, u16* __restrict__ wCtb)
{
    const int t = threadIdx.x;
    #pragma unroll
    for (int u = 0; u < 16; ++u){
        int idx = t + u * 256;
        fn1wb[idx] = f2us(fn1W[idx]);
        wAb[idx]   = f2us(fe2W[idx]);
        wBb[idx]   = f2us(fn2W[idx]);
        int n = idx >> 6, h = idx & 63;
        wCtb[idx]  = f2us(fe1W[h * 64 + n]);   // wCt[n][h] = fe1W[h][n]
    }
}

// ------------- prep: Wv[i][j][k][h] fp32 -> Wvtb[i*NJ+j][h][k] bf16 -------------
__global__ __launch_bounds__(256) void k_prep_wv(const float* __restrict__ Wv,
                                                 u16* __restrict__ Wvtb)
{
    __shared__ u16 t_l[64 * 66];
    const int ij = blockIdx.x;
    const int t  = threadIdx.x;
    const float* src = Wv + (size_t)ij * 4096;
    #pragma unroll
    for (int u = 0; u < 16; ++u){
        int idx = t + u * 256;            // = k*64 + h
        int k = idx >> 6, h = idx & 63;
        t_l[k * 66 + h] = f2us(src[idx]);
    }
    __syncthreads();
    u32* dst = (u32*)Wvtb + (size_t)ij * 2048;
    #pragma unroll
    for (int u = 0; u < 8; ++u){
        int q = t + u * 256;              // pair index: h*32 + k2
        int h = q >> 5, k2 = q & 31;
        u32 lo = t_l[(2 * k2) * 66 + h];
        u32 hi = t_l[(2 * k2 + 1) * 66 + h];
        dst[q] = lo | (hi << 16);
    }
}

// ---------------- Kernel A: xc = gelu(x @ Wcap + Bcap), bf16 out ----------------
__global__ __launch_bounds__(256) void k_xc(const float* __restrict__ x,
    const float* __restrict__ Wcap, const float* __restrict__ Bcap,
    u16* __restrict__ xcb)
{
    __shared__ float a_l[64][65];
    __shared__ float b_l[64][68];
    const int n0 = blockIdx.x * 64;
    const int i  = blockIdx.y;
    const int t  = threadIdx.x;
    const int tr = t >> 4, tc = t & 15;
    float acc[4][4] = {};
    for (int k0 = 0; k0 < DD; k0 += 64){
        #pragma unroll
        for (int u = 0; u < 16; ++u){
            int idx = t + u * 256;
            int r = idx >> 6, c = idx & 63;
            a_l[r][c] = x[(size_t)(n0 + r) * (NI * DD) + (size_t)i * DD + k0 + c];
            b_l[r][c] = Wcap[(size_t)i * (DD * HI) + (size_t)(k0 + r) * HI + c];
        }
        __syncthreads();
        #pragma unroll 8
        for (int k = 0; k < 64; ++k){
            float av[4];
            #pragma unroll
            for (int q = 0; q < 4; ++q) av[q] = a_l[tr * 4 + q][k];
            float4 bv = *(const float4*)&b_l[k][tc * 4];
            #pragma unroll
            for (int q = 0; q < 4; ++q){
                acc[q][0] += av[q] * bv.x; acc[q][1] += av[q] * bv.y;
                acc[q][2] += av[q] * bv.z; acc[q][3] += av[q] * bv.w;
            }
        }
        __syncthreads();
    }
    #pragma unroll
    for (int q = 0; q < 4; ++q){
        int n = n0 + tr * 4 + q;
        float vv[4];
        #pragma unroll
        for (int p = 0; p < 4; ++p)
            vv[p] = gelu_exact(acc[q][p] + Bcap[i * HI + tc * 4 + p]);
        u32 p0 = (u32)f2us(vv[0]) | ((u32)f2us(vv[1]) << 16);
        u32 p1 = (u32)f2us(vv[2]) | ((u32)f2us(vv[3]) << 16);
        *(uint2*)&xcb[((size_t)n * NI + i) * HI + tc * 4] = make_uint2(p0, p1);
    }
}

// ---------------- Fused: votes MFMA -> LDS, softmax, routing iters ----------------
// grid 512 = (32 n-chunks x 16 j), block 512 (8 waves). LDS ~156.5 KB, 1 block/CU.
// v_l: rows R = n*64+i (128 B each, bf16 h-major), XOR-swizzled:
//   byte(R, c) = R*128 + (c ^ (((R ^ (R>>6)) & 7) << 4))   -- mixes both n and i axes.
__global__ __launch_bounds__(512) void k_fused(
    const u16* __restrict__ xcb, const u16* __restrict__ Wvtb,
    const float* __restrict__ Bv, const float* __restrict__ mask,
    const u16* __restrict__ fn1wb, const float* __restrict__ fn1b,
    const float* __restrict__ scoreW, const float* __restrict__ scoreb,
    const float* __restrict__ alphaW, const float* __restrict__ alphab,
    const u16* __restrict__ wAb, const float* __restrict__ fe2b,
    const u16* __restrict__ wBb, const float* __restrict__ fn2b,
    const u16* __restrict__ wCtb, const float* __restrict__ fe1b,
    const int* __restrict__ itersp, float* __restrict__ out)
{
    __shared__ u16  v_l[65536];                 // 128 KB votes tile (swizzled)
    __shared__ float m_l[NT * 65];
    __shared__ float aij_l[NT * 65];
    __shared__ float M_l[NT * 65];
    __shared__ float vj_l[NT * 65];
    __shared__ float g_l[NT * 65];
    __shared__ float w_l[NT * 65];
    __shared__ float u_l[NT * 65];
    __shared__ float c_l[NT];

    // bijective XCD swizzle: XCD x gets j = 2x (round 1), 2x+1 (round 2)
    const int bid = blockIdx.x;
    const int j   = 2 * (bid & 7) + (bid >> 8);
    const int n0  = ((bid >> 3) & 31) * NT;

    const int t  = threadIdx.x;
    const int wv = t >> 6;
    const int l  = t & 63;
    const int lr = l & 15;
    const int lg = l >> 4;

    // stage mask tile
    #pragma unroll
    for (int q2 = 0; q2 < 2; ++q2){
        int idx = t + 512 * q2;
        int n = idx >> 6, i2 = idx & 63;
        m_l[n * 65 + i2] = mask[(size_t)(n0 + n) * NI + i2];
    }
    __syncthreads();

    // ---- votes phase: wave wv handles i in [8wv, 8wv+8) ----
    float swreg[16];
    #pragma unroll
    for (int ht = 0; ht < 4; ++ht)
        #pragma unroll
        for (int r = 0; r < 4; ++r)
            swreg[ht * 4 + r] = scoreW[ht * 16 + lg * 4 + r];
    const float sb = scoreb[0];

    for (int ii = 0; ii < 8; ++ii){
        const int i = 8 * wv + ii;
        // B frags: xc rows (lane lr -> n)
        const u16* xrow = xcb + ((size_t)(n0 + lr) * NI + i) * HI + lg * 8;
        bf16x8 b0 = *(const bf16x8*)(xrow);
        bf16x8 b1 = *(const bf16x8*)(xrow + 32);
        const u16* wvb = Wvtb + ((size_t)(i * NJ + j)) * 4096;
        const float* bvp = Bv + ((size_t)i * NJ + j) * HO;
        const float mk = m_l[lr * 65 + i];
        char* vrow = (char*)v_l + (lr * 64 + i) * 128;
        const int sw = ((lr ^ i) & 7) << 4;
        float p = 0.f;
        #pragma unroll
        for (int ht = 0; ht < 4; ++ht){
            const u16* ar = wvb + (ht * 16 + lr) * 64 + lg * 8;
            bf16x8 a0 = *(const bf16x8*)(ar);
            bf16x8 a1 = *(const bf16x8*)(ar + 32);
            f32x4 c = {};
            c = __builtin_amdgcn_mfma_f32_16x16x32_bf16(a0, b0, c, 0, 0, 0);
            c = __builtin_amdgcn_mfma_f32_16x16x32_bf16(a1, b1, c, 0, 0, 0);
            // lane: col n = lr; rows h = ht*16 + lg*4 + r
            float vals[4];
            #pragma unroll
            for (int r = 0; r < 4; ++r){
                vals[r] = (c[r] + bvp[ht * 16 + lg * 4 + r]) * mk;
                p += vals[r] * swreg[ht * 4 + r];
            }
            u32 lo = (u32)f2us(vals[0]) | ((u32)f2us(vals[1]) << 16);
            u32 hi = (u32)f2us(vals[2]) | ((u32)f2us(vals[3]) << 16);
            *(uint2*)(vrow + ((ht * 32 + lg * 8) ^ sw)) = make_uint2(lo, hi);
        }
        p += __shfl_xor(p, 16);
        p += __shfl_xor(p, 32);
        if (lg == 0) aij_l[lr * 65 + i] = p + sb;   // bij
    }
    __syncthreads();

    // ---- softmax over i (per n; wave wv -> n = wv, wv+8) ----
    #pragma unroll
    for (int p2 = 0; p2 < 2; ++p2){
        int n = wv + 8 * p2;
        float mk = m_l[n * 65 + l];
        float att = (mk == 0.f) ? -3.0e38f : 0.f;
        float s = aij_l[n * 65 + l] * mk + att;
        float mx = s;
        #pragma unroll
        for (int off = 32; off; off >>= 1) mx = fmaxf(mx, __shfl_xor(mx, off));
        float pe = __expf(s - mx);
        float sm = pe;
        #pragma unroll
        for (int off = 32; off; off >>= 1) sm += __shfl_xor(sm, off);
        aij_l[n * 65 + l] = pe / sm;
    }
    __syncthreads();

    const int iters = itersp[0];
    for (int it = 0; it < iters; ++it){
        // ---- nv[n][h] = sum_i aij * votes; vj update ----
        #pragma unroll
        for (int p2 = 0; p2 < 2; ++p2){
            int n = wv + 8 * p2;
            const char* vbase = (const char*)v_l + n * 64 * 128;
            int h2 = l * 2;
            float acc = 0.f;
            #pragma unroll 8
            for (int i = 0; i < 64; ++i){
                float a = aij_l[n * 65 + i];
                int sw = ((i ^ n) & 7) << 4;
                acc += a * us2f(*(const u16*)(vbase + i * 128 + (h2 ^ sw)));
            }
            float nv = gelu_exact(acc);
            if (it == 0){
                vj_l[n * 65 + l] = nv;
            } else {
                float dv = nv * alphaW[l];
                #pragma unroll
                for (int off = 32; off; off >>= 1) dv += __shfl_xor(dv, off);
                float alpha = sigm(dv + alphab[0]);
                vj_l[n * 65 + l] = alpha * nv + (1.f - alpha) * vj_l[n * 65 + l];
            }
        }
        __syncthreads();
        if (it == iters - 1) break;

        // ---- g = fe2(vj), w = fn2(vj) ----
        #pragma unroll
        for (int p2 = 0; p2 < 2; ++p2){
            int n = wv + 8 * p2;
            const uint4* wa = (const uint4*)(wAb + l * 64);
            const uint4* wb = (const uint4*)(wBb + l * 64);
            float a = 0.f, b = 0.f;
            #pragma unroll
            for (int c = 0; c < 8; ++c){
                a += dot8(wa[c], &vj_l[n * 65 + c * 8]);
                b += dot8(wb[c], &vj_l[n * 65 + c * 8]);
            }
            g_l[n * 65 + l] = a + fe2b[l];
            w_l[n * 65 + l] = b + fn2b[l];
        }
        __syncthreads();

        // ---- u = fe1W^T g, c = fe1b.g (VALU) ; M via fn_v-recompute MFMA ----
        #pragma unroll
        for (int p2 = 0; p2 < 2; ++p2){
            int n = wv + 8 * p2;
            const uint4* wc = (const uint4*)(wCtb + l * 64);
            float a = 0.f;
            #pragma unroll
            for (int c = 0; c < 8; ++c) a += dot8(wc[c], &g_l[n * 65 + c * 8]);
            u_l[n * 65 + l] = a;
            float cv = fe1b[l] * g_l[n * 65 + l];
            #pragma unroll
            for (int off = 32; off; off >>= 1) cv += __shfl_xor(cv, off);
            if (l == 0) c_l[n] = cv;
        }
        #pragma unroll
        for (int q = 0; q < 8; ++q){
            int Rt = wv * 8 + q;
            int n  = Rt >> 2;
            int R  = Rt * 16 + lr;
            const char* vrow = (const char*)v_l + R * 128;
            int sw = ((R ^ n) & 7) << 4;
            bf16x8 vb0 = *(const bf16x8*)(vrow + ((lg * 16) ^ sw));
            bf16x8 vb1 = *(const bf16x8*)(vrow + ((lg * 16 + 64) ^ sw));
            float mpart = 0.f;
            #pragma unroll
            for (int ht = 0; ht < 4; ++ht){
                const u16* ar = fn1wb + (ht * 16 + lr) * 64 + lg * 8;
                bf16x8 a0 = *(const bf16x8*)(ar);
                bf16x8 a1 = *(const bf16x8*)(ar + 32);
                f32x4 c = {};
                c = __builtin_amdgcn_mfma_f32_16x16x32_bf16(a0, vb0, c, 0, 0, 0);
                c = __builtin_amdgcn_mfma_f32_16x16x32_bf16(a1, vb1, c, 0, 0, 0);
                #pragma unroll
                for (int r = 0; r < 4; ++r){
                    int hn = ht * 16 + lg * 4 + r;
                    mpart += fabsf(c[r] + fn1b[hn] - w_l[n * 65 + hn]);
                }
            }
            mpart += __shfl_xor(mpart, 16);
            mpart += __shfl_xor(mpart, 32);
            if (lg == 0) M_l[n * 65 + (Rt & 3) * 16 + lr] = -mpart;
        }
        __syncthreads();

        // ---- E = votes.u + c ; aij = tanh(E)*sigm(M*mk + att) ----
        #pragma unroll
        for (int p2 = 0; p2 < 2; ++p2){
            int R = t + 512 * p2;
            int n = R >> 6, i = l;
            const char* vrow = (const char*)v_l + R * 128;
            int sw = ((R ^ n) & 7) << 4;
            float e = c_l[n];
            #pragma unroll 8
            for (int hp = 0; hp < 32; ++hp){
                u32 qv = *(const u32*)(vrow + ((hp * 4) ^ sw));
                e += bflo(qv) * u_l[n * 65 + 2 * hp]
                   + bfhi(qv) * u_l[n * 65 + 2 * hp + 1];
            }
            float mk = m_l[n * 65 + i];
            float att = (mk == 0.f) ? -3.0e38f : 0.f;
            aij_l[n * 65 + i] = tanhf(e) * sigm(M_l[n * 65 + i] * mk + att);
        }
        __syncthreads();
    }

    // ---- output ----
    #pragma unroll
    for (int p2 = 0; p2 < 2; ++p2){
        int n = wv + 8 * p2;
        out[((size_t)(n0 + n) * NJ + j) * HO + l] = vj_l[n * 65 + l];
    }
}

extern "C" void kernel_launch(void* const* d_in, const int* in_sizes, int n_in,
                              void* d_out, int out_size, void* d_ws, size_t ws_size,
                              hipStream_t stream)
{
    (void)in_sizes; (void)n_in; (void)out_size; (void)ws_size;
    const float* x      = (const float*)d_in[0];
    const float* mask   = (const float*)d_in[1];
    const float* Wcap   = (const float*)d_in[2];
    const float* Bcap   = (const float*)d_in[3];
    const float* Wv     = (const float*)d_in[4];
    const float* Bv     = (const float*)d_in[5];
    const float* scoreW = (const float*)d_in[6];
    const float* scoreb = (const float*)d_in[7];
    const float* alphaW = (const float*)d_in[8];
    const float* alphab = (const float*)d_in[9];
    const float* fe1W   = (const float*)d_in[10];
    const float* fe1b   = (const float*)d_in[11];
    const float* fe2W   = (const float*)d_in[12];
    const float* fe2b   = (const float*)d_in[13];
    const float* fn1W   = (const float*)d_in[14];
    const float* fn1b   = (const float*)d_in[15];
    const float* fn2W   = (const float*)d_in[16];
    const float* fn2b   = (const float*)d_in[17];
    const int*   itersp = (const int*)d_in[18];
    float* out = (float*)d_out;

    char* ws = (char*)d_ws;
    u16* xcb   = (u16*)ws;                    //  4,194,304 B
    u16* Wvtb  = (u16*)(ws + 4194304);        //  8,388,608 B
    u16* fn1wb = (u16*)(ws + 12582912);       //      8,192 B
    u16* wAb   = (u16*)(ws + 12591104);       //      8,192 B
    u16* wBb   = (u16*)(ws + 12599296);       //      8,192 B
    u16* wCtb  = (u16*)(ws + 12607488);       //      8,192 B  (total ~12.6 MB)

    k_prep_small<<<1, 256, 0, stream>>>(fn1W, fe2W, fn2W, fe1W, fn1wb, wAb, wBb, wCtb);
    k_prep_wv   <<<1024, 256, 0, stream>>>(Wv, Wvtb);
    k_xc        <<<dim3(8, 64), 256, 0, stream>>>(x, Wcap, Bcap, xcb);
    k_fused     <<<512, 512, 0, stream>>>(xcb, Wvtb, Bv, mask, fn1wb, fn1b,
                                          scoreW, scoreb, alphaW, alphab,
                                          wAb, fe2b, wBb, fn2b, wCtb, fe1b,
                                          itersp, out);
}

// Round 4
// 251.136 us; speedup vs baseline: 1.0747x; 1.0747x over previous
//
#include <hip/hip_runtime.h>
#include <hip/hip_bf16.h>

#define NN 512
#define NI 64
#define NJ 16
#define DD 256
#define HI 64
#define HO 64

typedef unsigned int  u32;
typedef unsigned short u16;

typedef __attribute__((ext_vector_type(8))) short bf16x8;
typedef __attribute__((ext_vector_type(4))) float f32x4;

__device__ __forceinline__ float gelu_exact(float x){
    return 0.5f * x * (1.0f + erff(x * 0.7071067811865476f));
}
__device__ __forceinline__ float sigm(float x){
    return 1.0f / (1.0f + __expf(-x));
}
__device__ __forceinline__ float us2f(u16 u){
    union { u32 ui; float f; } cv; cv.ui = ((u32)u) << 16; return cv.f;
}
__device__ __forceinline__ float bflo(u32 x){
    union { u32 u; float f; } c; c.u = x << 16; return c.f;
}
__device__ __forceinline__ float bfhi(u32 x){
    union { u32 u; float f; } c; c.u = x & 0xffff0000u; return c.f;
}
__device__ __forceinline__ u16 f2us(float f){
    union { float f; u32 u; } cv; cv.f = f;
    u32 r = cv.u + 0x7FFFu + ((cv.u >> 16) & 1u);   // RNE
    return (u16)(r >> 16);
}
__device__ __forceinline__ float dot8(uint4 q, const float* v){
    return bflo(q.x) * v[0] + bfhi(q.x) * v[1]
         + bflo(q.y) * v[2] + bfhi(q.y) * v[3]
         + bflo(q.z) * v[4] + bfhi(q.z) * v[5]
         + bflo(q.w) * v[6] + bfhi(q.w) * v[7];
}

// ------------- prep: small weights -> bf16 (fe1W transposed) -------------
__global__ __launch_bounds__(256) void k_prep_small(
    const float* __restrict__ fn1W, const float* __restrict__ fe2W,
    const float* __restrict__ fn2W, const float* __restrict__ fe1W,
    u16* __restrict__ fn1wb, u16* __restrict__ wAb,
    u16* __restrict__ wBb, u16* __restrict__ wCtb)
{
    const int t = threadIdx.x;
    #pragma unroll
    for (int u = 0; u < 16; ++u){
        int idx = t + u * 256;
        fn1wb[idx] = f2us(fn1W[idx]);
        wAb[idx]   = f2us(fe2W[idx]);
        wBb[idx]   = f2us(fn2W[idx]);
        int n = idx >> 6, h = idx & 63;
        wCtb[idx]  = f2us(fe1W[h * 64 + n]);   // wCt[n][h] = fe1W[h][n]
    }
}

// ---------------- Kernel A: xc = gelu(x @ Wcap + Bcap), bf16 out ----------------
// grid 512 linear; XCD-bijective swizzle: blocks with same i-octet -> same XCD
// so the Wcap slice (8 x 64 KB) stays L2-resident. HBM: 168 -> ~50 MB.
__global__ __launch_bounds__(256) void k_xc(const float* __restrict__ x,
    const float* __restrict__ Wcap, const float* __restrict__ Bcap,
    u16* __restrict__ xcb)
{
    __shared__ float a_l[64][65];
    __shared__ float b_l[64][68];
    const int id = blockIdx.x;
    const int i  = ((id & 7) << 3) | (id >> 6);   // id%8 = i>>3 -> XCD
    const int nc = (id >> 3) & 7;
    const int n0 = nc * 64;
    const int t  = threadIdx.x;
    const int tr = t >> 4, tc = t & 15;
    float acc[4][4] = {};
    for (int k0 = 0; k0 < DD; k0 += 64){
        #pragma unroll
        for (int u = 0; u < 16; ++u){
            int idx = t + u * 256;
            int r = idx >> 6, c = idx & 63;
            a_l[r][c] = x[(size_t)(n0 + r) * (NI * DD) + (size_t)i * DD + k0 + c];
            b_l[r][c] = Wcap[(size_t)i * (DD * HI) + (size_t)(k0 + r) * HI + c];
        }
        __syncthreads();
        #pragma unroll 8
        for (int k = 0; k < 64; ++k){
            float av[4];
            #pragma unroll
            for (int q = 0; q < 4; ++q) av[q] = a_l[tr * 4 + q][k];
            float4 bv = *(const float4*)&b_l[k][tc * 4];
            #pragma unroll
            for (int q = 0; q < 4; ++q){
                acc[q][0] += av[q] * bv.x; acc[q][1] += av[q] * bv.y;
                acc[q][2] += av[q] * bv.z; acc[q][3] += av[q] * bv.w;
            }
        }
        __syncthreads();
    }
    #pragma unroll
    for (int q = 0; q < 4; ++q){
        int n = n0 + tr * 4 + q;
        float vv[4];
        #pragma unroll
        for (int p = 0; p < 4; ++p)
            vv[p] = gelu_exact(acc[q][p] + Bcap[i * HI + tc * 4 + p]);
        u32 p0 = (u32)f2us(vv[0]) | ((u32)f2us(vv[1]) << 16);
        u32 p1 = (u32)f2us(vv[2]) | ((u32)f2us(vv[3]) << 16);
        *(uint2*)&xcb[((size_t)n * NI + i) * HI + tc * 4] = make_uint2(p0, p1);
    }
}

// ------- Kernel B: barrier-free MFMA votes (masked, bf16) + bij -------
// grid (8 nc, 16 j, 64 i), block 256 = 4 independent waves (16-n strips).
// B-frags built directly from fp32 Wv (RNE convert in reg). No fnv (route
// recomputes it). Per-wave 2 KB swizzled LDS strip for coalesced stores.
__global__ __launch_bounds__(256) void k_votes(
    const u16* __restrict__ xcb, const float* __restrict__ Wv,
    const float* __restrict__ Bv, const float* __restrict__ mask,
    const float* __restrict__ scoreW, const float* __restrict__ scoreb,
    u16* __restrict__ votes, float* __restrict__ bij)
{
    __shared__ u16 strip[4][16][64];
    const int nc = blockIdx.x, j = blockIdx.y, i = blockIdx.z;
    const int t = threadIdx.x, w = t >> 6, l = t & 63;
    const int lr = l & 15, lg = l >> 4;
    const int n0 = nc * 64 + 16 * w;

    // A frags: xc rows (lane lr -> n-row, lg -> k-group)
    const u16* arow = xcb + ((size_t)(n0 + lr) * NI + i) * HI + lg * 8;
    bf16x8 a0 = *(const bf16x8*)arow;
    bf16x8 a1 = *(const bf16x8*)(arow + 32);

    const float* wvp = Wv + (size_t)(i * NJ + j) * 4096;   // [k][h] fp32
    const float* bvp = Bv + (size_t)(i * NJ + j) * HO;

    float mk[4];
    #pragma unroll
    for (int r = 0; r < 4; ++r)
        mk[r] = mask[(size_t)(n0 + lg * 4 + r) * NI + i];

    float p[4] = {};
    #pragma unroll
    for (int ht = 0; ht < 4; ++ht){
        const int h = ht * 16 + lr;
        bf16x8 b0, b1;
        #pragma unroll
        for (int e = 0; e < 8; ++e){
            b0[e] = (short)f2us(wvp[(lg * 8 + e) * 64 + h]);
            b1[e] = (short)f2us(wvp[(32 + lg * 8 + e) * 64 + h]);
        }
        f32x4 c4 = {};
        c4 = __builtin_amdgcn_mfma_f32_16x16x32_bf16(a0, b0, c4, 0, 0, 0);
        c4 = __builtin_amdgcn_mfma_f32_16x16x32_bf16(a1, b1, c4, 0, 0, 0);
        const float bv = bvp[h];
        const float sw = scoreW[h];
        #pragma unroll
        for (int r = 0; r < 4; ++r){
            const int row = lg * 4 + r;              // n within strip
            float val = (c4[r] + bv) * mk[r];
            p[r] += val * sw;
            strip[w][row][h ^ ((row & 7) << 3)] = f2us(val);  // XOR-swizzled
        }
    }
    // bij = votes . scoreW (+b), reduce over the 16 h-lanes per (n)
    #pragma unroll
    for (int r = 0; r < 4; ++r){
        float s = p[r];
        s += __shfl_xor(s, 1); s += __shfl_xor(s, 2);
        s += __shfl_xor(s, 4); s += __shfl_xor(s, 8);
        if (lr == 0)
            bij[((size_t)(n0 + lg * 4 + r) * NJ + j) * NI + i] = s + scoreb[0];
    }

    // coalesced writeout (intra-wave LDS ordering, no barrier)
    {
        const int row = l >> 2, c0 = (l & 3) * 16;
        const int rs = (row & 7) << 3;
        uint4 q0 = *(const uint4*)&strip[w][row][c0 ^ rs];
        uint4 q1 = *(const uint4*)&strip[w][row][(c0 + 8) ^ rs];
        size_t off = ((size_t)(n0 + row) * NJ + j) * (size_t)(NI * HO)
                   + (size_t)i * HO + c0;
        *(uint4*)(votes + off)     = q0;
        *(uint4*)(votes + off + 8) = q1;
    }
}

// ---------------- Kernel C: routing, one wave per (n,j), zero barriers ----------------
// grid 2048, block 256 = 4 independent waves. Per wave: votes row in regs (dr),
// 8 KB XOR-swizzled v_l for nv + fn_v-recompute MFMA; M kept in-lane.
// LDS 37.9 KB/block -> 4 blocks/CU = 16 waves/CU.
__global__ __launch_bounds__(256, 4) void k_route(
    const u16* __restrict__ votes, const float* __restrict__ bijg,
    const float* __restrict__ mask,
    const float* __restrict__ alphaW, const float* __restrict__ alphab,
    const u16* __restrict__ wAb, const float* __restrict__ fe2b,
    const u16* __restrict__ wBb, const float* __restrict__ fn2b,
    const u16* __restrict__ wCtb, const float* __restrict__ fe1b,
    const u16* __restrict__ fn1wb, const float* __restrict__ fn1b,
    const int* __restrict__ itersp, float* __restrict__ out)
{
    __shared__ u16  v_l[4][64][64];
    __shared__ float s_aij[4][64];
    __shared__ float s_vj[4][64];
    __shared__ float s_g[4][64];
    __shared__ float s_w[4][64];
    __shared__ float s_u[4][64];

    const int t = threadIdx.x;
    const int wid = t >> 6;
    const int l = t & 63;
    const int lr = l & 15, lg = l >> 4;
    const int pair = blockIdx.x * 4 + wid;
    const int n = pair >> 4, j = pair & 15;

    const size_t base = ((size_t)n * NJ + j) * (size_t)(NI * HO);
    uint4 dr[8];                                   // votes row i = l
    const uint4* vp = (const uint4*)(votes + base + (size_t)l * HO);
    #pragma unroll
    for (int c = 0; c < 8; ++c) dr[c] = vp[c];
    #pragma unroll
    for (int c = 0; c < 8; ++c)                    // swizzled LDS copy
        *(uint4*)&v_l[wid][l][(c * 8) ^ ((l & 7) << 3)] = dr[c];

    const float mki  = mask[(size_t)n * NI + l];
    const float atti = (mki == 0.f) ? -3.0e38f : 0.f;

    {   // softmax over i
        float b = bijg[((size_t)n * NJ + j) * NI + l];
        float s = b * mki + atti;
        float mx = s;
        #pragma unroll
        for (int off = 32; off; off >>= 1) mx = fmaxf(mx, __shfl_xor(mx, off));
        float pe = __expf(s - mx);
        float sm = pe;
        #pragma unroll
        for (int off = 32; off; off >>= 1) sm += __shfl_xor(sm, off);
        s_aij[wid][l] = pe / sm;
    }

    const int iters = itersp[0];
    float vj = 0.f;                                // lane l owns vj[h=l]
    for (int it = 0; it < iters; ++it){
        // nv[h=l] = sum_i aij[i]*votes[i][h]  (row-major swizzled reads, conflict-free)
        float acc = 0.f;
        const int hsw = l & ~1;
        #pragma unroll 8
        for (int i2 = 0; i2 < 64; ++i2){
            u32 q = *(const u32*)&v_l[wid][i2][hsw ^ ((i2 & 7) << 3)];
            float ve = (l & 1) ? bfhi(q) : bflo(q);
            acc += s_aij[wid][i2] * ve;
        }
        float nv = gelu_exact(acc);
        if (it == 0) vj = nv;
        else {
            float dv = nv * alphaW[l];
            #pragma unroll
            for (int off = 32; off; off >>= 1) dv += __shfl_xor(dv, off);
            float alpha = sigm(dv + alphab[0]);
            vj = alpha * nv + (1.f - alpha) * vj;
        }
        if (it == iters - 1) break;
        s_vj[wid][l] = vj;

        // g = fe2(vj), w = fn2(vj)   (lane h = l)
        const uint4* wa  = (const uint4*)(wAb + l * 64);
        const uint4* wbp = (const uint4*)(wBb + l * 64);
        float ga = 0.f, wacc = 0.f;
        #pragma unroll
        for (int c = 0; c < 8; ++c){
            ga   += dot8(wa[c],  &s_vj[wid][c * 8]);
            wacc += dot8(wbp[c], &s_vj[wid][c * 8]);
        }
        float g = ga + fe2b[l];
        s_g[wid][l] = g;
        s_w[wid][l] = wacc + fn2b[l];

        // u = fe1W^T g ; cv = fe1b . g (all lanes)
        const uint4* wc = (const uint4*)(wCtb + l * 64);
        float ua = 0.f;
        #pragma unroll
        for (int c = 0; c < 8; ++c) ua += dot8(wc[c], &s_g[wid][c * 8]);
        s_u[wid][l] = ua;
        float cv = fe1b[l] * g;
        #pragma unroll
        for (int off = 32; off; off >>= 1) cv += __shfl_xor(cv, off);

        // M[i] via fn_v recompute (MFMA, B from swizzled v_l)
        float Mreg = 0.f;
        #pragma unroll
        for (int itile = 0; itile < 4; ++itile){
            const int row = itile * 16 + lr;       // i-row
            const u16* vr = &v_l[wid][row][0];
            const int rs = (row & 7) << 3;
            bf16x8 vb0 = *(const bf16x8*)(vr + ((lg * 8) ^ rs));
            bf16x8 vb1 = *(const bf16x8*)(vr + ((32 + lg * 8) ^ rs));
            float mpart = 0.f;
            #pragma unroll
            for (int ht = 0; ht < 4; ++ht){
                const u16* ar = fn1wb + (ht * 16 + lr) * 64 + lg * 8;
                bf16x8 a0 = *(const bf16x8*)ar;
                bf16x8 a1 = *(const bf16x8*)(ar + 32);
                f32x4 c4 = {};
                c4 = __builtin_amdgcn_mfma_f32_16x16x32_bf16(a0, vb0, c4, 0, 0, 0);
                c4 = __builtin_amdgcn_mfma_f32_16x16x32_bf16(a1, vb1, c4, 0, 0, 0);
                #pragma unroll
                for (int r = 0; r < 4; ++r){
                    int hn = ht * 16 + lg * 4 + r;
                    mpart += fabsf(c4[r] + fn1b[hn] - s_w[wid][hn]);
                }
            }
            mpart += __shfl_xor(mpart, 16);
            mpart += __shfl_xor(mpart, 32);
            if (lg == itile) Mreg = -mpart;        // lands in lane l = i
        }

        // E = votes.u + cv ; aij update (lane i = l, dr in regs)
        float e = cv;
        #pragma unroll
        for (int c = 0; c < 8; ++c) e += dot8(dr[c], &s_u[wid][c * 8]);
        s_aij[wid][l] = tanhf(e) * sigm(Mreg * mki + atti);
    }

    out[((size_t)n * NJ + j) * HO + l] = vj;
}

extern "C" void kernel_launch(void* const* d_in, const int* in_sizes, int n_in,
                              void* d_out, int out_size, void* d_ws, size_t ws_size,
                              hipStream_t stream)
{
    (void)in_sizes; (void)n_in; (void)out_size; (void)ws_size;
    const float* x      = (const float*)d_in[0];
    const float* mask   = (const float*)d_in[1];
    const float* Wcap   = (const float*)d_in[2];
    const float* Bcap   = (const float*)d_in[3];
    const float* Wv     = (const float*)d_in[4];
    const float* Bv     = (const float*)d_in[5];
    const float* scoreW = (const float*)d_in[6];
    const float* scoreb = (const float*)d_in[7];
    const float* alphaW = (const float*)d_in[8];
    const float* alphab = (const float*)d_in[9];
    const float* fe1W   = (const float*)d_in[10];
    const float* fe1b   = (const float*)d_in[11];
    const float* fe2W   = (const float*)d_in[12];
    const float* fe2b   = (const float*)d_in[13];
    const float* fn1W   = (const float*)d_in[14];
    const float* fn1b   = (const float*)d_in[15];
    const float* fn2W   = (const float*)d_in[16];
    const float* fn2b   = (const float*)d_in[17];
    const int*   itersp = (const int*)d_in[18];
    float* out = (float*)d_out;

    char* ws = (char*)d_ws;
    u16*   xcb   = (u16*)ws;                      //  4,194,304 B
    u16*   vts   = (u16*)(ws + 4194304);          // 67,108,864 B
    float* bij   = (float*)(ws + 71303168);       //  2,097,152 B
    u16*   fn1wb = (u16*)(ws + 73400320);         //      8,192 B
    u16*   wAb   = (u16*)(ws + 73408512);         //      8,192 B
    u16*   wBb   = (u16*)(ws + 73416704);         //      8,192 B
    u16*   wCtb  = (u16*)(ws + 73424896);         //      8,192 B  (~73.4 MB)

    k_prep_small<<<1, 256, 0, stream>>>(fn1W, fe2W, fn2W, fe1W, fn1wb, wAb, wBb, wCtb);
    k_xc        <<<512, 256, 0, stream>>>(x, Wcap, Bcap, xcb);
    k_votes     <<<dim3(8, 16, 64), 256, 0, stream>>>(xcb, Wv, Bv, mask,
                                                      scoreW, scoreb, vts, bij);
    k_route     <<<2048, 256, 0, stream>>>(vts, bij, mask, alphaW, alphab,
                                           wAb, fe2b, wBb, fn2b, wCtb, fe1b,
                                           fn1wb, fn1b, itersp, out);
}

// Round 5
// 185.192 us; speedup vs baseline: 1.4574x; 1.3561x over previous
//
#include <hip/hip_runtime.h>
#include <hip/hip_bf16.h>

#define NN 512
#define NI 64
#define NJ 16
#define DD 256
#define HI 64
#define HO 64

typedef unsigned int  u32;
typedef unsigned short u16;

typedef __attribute__((ext_vector_type(8))) short bf16x8;
typedef __attribute__((ext_vector_type(4))) float f32x4;

__device__ __forceinline__ float gelu_exact(float x){
    return 0.5f * x * (1.0f + erff(x * 0.7071067811865476f));
}
__device__ __forceinline__ float sigm(float x){
    return 1.0f / (1.0f + __expf(-x));
}
__device__ __forceinline__ float us2f(u16 u){
    union { u32 ui; float f; } cv; cv.ui = ((u32)u) << 16; return cv.f;
}
__device__ __forceinline__ float bflo(u32 x){
    union { u32 u; float f; } c; c.u = x << 16; return c.f;
}
__device__ __forceinline__ float bfhi(u32 x){
    union { u32 u; float f; } c; c.u = x & 0xffff0000u; return c.f;
}
__device__ __forceinline__ u16 f2us(float f){
    union { float f; u32 u; } cv; cv.f = f;
    u32 r = cv.u + 0x7FFFu + ((cv.u >> 16) & 1u);   // RNE
    return (u16)(r >> 16);
}
__device__ __forceinline__ float dot8(uint4 q, const float* v){
    return bflo(q.x) * v[0] + bfhi(q.x) * v[1]
         + bflo(q.y) * v[2] + bfhi(q.y) * v[3]
         + bflo(q.z) * v[4] + bfhi(q.z) * v[5]
         + bflo(q.w) * v[6] + bfhi(q.w) * v[7];
}

// ------------- prep: small weights -> bf16 (fe1W transposed) -------------
__global__ __launch_bounds__(256) void k_prep_small(
    const float* __restrict__ fn1W, const float* __restrict__ fe2W,
    const float* __restrict__ fn2W, const float* __restrict__ fe1W,
    u16* __restrict__ fn1wb, u16* __restrict__ wAb,
    u16* __restrict__ wBb, u16* __restrict__ wCtb)
{
    const int t = threadIdx.x;
    #pragma unroll
    for (int u = 0; u < 16; ++u){
        int idx = t + u * 256;
        fn1wb[idx] = f2us(fn1W[idx]);
        wAb[idx]   = f2us(fe2W[idx]);
        wBb[idx]   = f2us(fn2W[idx]);
        int n = idx >> 6, h = idx & 63;
        wCtb[idx]  = f2us(fe1W[h * 64 + n]);   // wCt[n][h] = fe1W[h][n]
    }
}

// ---------------- Kernel A: xc = gelu(x @ Wcap + Bcap), bf16 out ----------------
__global__ __launch_bounds__(256) void k_xc(const float* __restrict__ x,
    const float* __restrict__ Wcap, const float* __restrict__ Bcap,
    u16* __restrict__ xcb)
{
    __shared__ float a_l[64][65];
    __shared__ float b_l[64][68];
    const int id = blockIdx.x;
    const int i  = ((id & 7) << 3) | (id >> 6);   // id%8 = i>>3 -> XCD
    const int nc = (id >> 3) & 7;
    const int n0 = nc * 64;
    const int t  = threadIdx.x;
    const int tr = t >> 4, tc = t & 15;
    float acc[4][4] = {};
    for (int k0 = 0; k0 < DD; k0 += 64){
        #pragma unroll
        for (int u = 0; u < 16; ++u){
            int idx = t + u * 256;
            int r = idx >> 6, c = idx & 63;
            a_l[r][c] = x[(size_t)(n0 + r) * (NI * DD) + (size_t)i * DD + k0 + c];
            b_l[r][c] = Wcap[(size_t)i * (DD * HI) + (size_t)(k0 + r) * HI + c];
        }
        __syncthreads();
        #pragma unroll 8
        for (int k = 0; k < 64; ++k){
            float av[4];
            #pragma unroll
            for (int q = 0; q < 4; ++q) av[q] = a_l[tr * 4 + q][k];
            float4 bv = *(const float4*)&b_l[k][tc * 4];
            #pragma unroll
            for (int q = 0; q < 4; ++q){
                acc[q][0] += av[q] * bv.x; acc[q][1] += av[q] * bv.y;
                acc[q][2] += av[q] * bv.z; acc[q][3] += av[q] * bv.w;
            }
        }
        __syncthreads();
    }
    #pragma unroll
    for (int q = 0; q < 4; ++q){
        int n = n0 + tr * 4 + q;
        float vv[4];
        #pragma unroll
        for (int p = 0; p < 4; ++p)
            vv[p] = gelu_exact(acc[q][p] + Bcap[i * HI + tc * 4 + p]);
        u32 p0 = (u32)f2us(vv[0]) | ((u32)f2us(vv[1]) << 16);
        u32 p1 = (u32)f2us(vv[2]) | ((u32)f2us(vv[3]) << 16);
        *(uint2*)&xcb[((size_t)n * NI + i) * HI + tc * 4] = make_uint2(p0, p1);
    }
}

// ------- Kernel B: one block per (i,j); votes + fn_v (MFMA) + bij -------
// 1024 blocks x 256 thr (4 indep waves, 16-n strips), loop over 8 n-chunks.
// Wv -> bf16 B-frags built ONCE per block. Global tiles stored pre-swizzled:
// within each 128-B row (i), 16-B granule g lands at position g ^ (i&7).
__global__ __launch_bounds__(256) void k_votes(
    const u16* __restrict__ xcb, const float* __restrict__ Wv,
    const float* __restrict__ Bv, const float* __restrict__ mask,
    const u16* __restrict__ fn1wb, const float* __restrict__ fn1b,
    const float* __restrict__ scoreW, const float* __restrict__ scoreb,
    u16* __restrict__ votes, u16* __restrict__ fnv, float* __restrict__ bij)
{
    __shared__ u16 vstrip[4][1024];   // per-wave 16n x 64h (granule-swizzled by n&7)
    __shared__ u16 fstrip[4][1024];
    const int i = blockIdx.x, j = blockIdx.y;
    const int t = threadIdx.x, w = t >> 6, l = t & 63;
    const int lr = l & 15, lg = l >> 4;
    const int isw = i & 7;

    // one-time B-frags: Wv [k][h] fp32 -> bf16 (lane: h=ht*16+lr, k=lg*8..)
    bf16x8 wb0[4], wb1[4], nb0[4], nb1[4];
    const float* wvp = Wv + (size_t)(i * NJ + j) * 4096;
    float bv[4], f1b[4], swv[4];
    #pragma unroll
    for (int ht = 0; ht < 4; ++ht){
        const int h = ht * 16 + lr;
        #pragma unroll
        for (int e = 0; e < 8; ++e){
            wb0[ht][e] = (short)f2us(wvp[(lg * 8 + e) * 64 + h]);
            wb1[ht][e] = (short)f2us(wvp[(32 + lg * 8 + e) * 64 + h]);
        }
        const u16* q = fn1wb + h * 64 + lg * 8;
        nb0[ht] = *(const bf16x8*)q;
        nb1[ht] = *(const bf16x8*)(q + 32);
        bv[ht]  = Bv[(size_t)(i * NJ + j) * HO + h];
        f1b[ht] = fn1b[h];
        swv[ht] = scoreW[h];
    }
    const float sb = scoreb[0];
    u16* vst = vstrip[w];
    u16* fst = fstrip[w];

    for (int nc = 0; nc < 8; ++nc){
        const int n0 = nc * 64 + 16 * w;
        // A frags: xc rows (lane lr -> n-row)
        const u16* ar = xcb + ((size_t)(n0 + lr) * NI + i) * HI + lg * 8;
        bf16x8 a0 = *(const bf16x8*)ar;
        bf16x8 a1 = *(const bf16x8*)(ar + 32);
        float mk[4];
        #pragma unroll
        for (int r = 0; r < 4; ++r)
            mk[r] = mask[(size_t)(n0 + lg * 4 + r) * NI + i];

        float p[4] = {};
        #pragma unroll
        for (int ht = 0; ht < 4; ++ht){
            f32x4 c4 = {};
            c4 = __builtin_amdgcn_mfma_f32_16x16x32_bf16(a0, wb0[ht], c4, 0, 0, 0);
            c4 = __builtin_amdgcn_mfma_f32_16x16x32_bf16(a1, wb1[ht], c4, 0, 0, 0);
            const int h = ht * 16 + lr, gp = h >> 3;
            #pragma unroll
            for (int r = 0; r < 4; ++r){
                const int rs = lg * 4 + r;
                float val = (c4[r] + bv[ht]) * mk[r];
                p[r] += val * swv[ht];
                vst[rs * 64 + ((gp ^ (rs & 7)) << 3) + (h & 7)] = f2us(val);
            }
        }
        #pragma unroll
        for (int r = 0; r < 4; ++r){
            float s = p[r];
            s += __shfl_xor(s, 1); s += __shfl_xor(s, 2);
            s += __shfl_xor(s, 4); s += __shfl_xor(s, 8);
            if (lr == 0)
                bij[((size_t)(n0 + lg * 4 + r) * NJ + j) * NI + i] = s + sb;
        }

        // fn_v = votes_tile @ fn1W^T (A rows from own strip; granule lg / lg+4)
        const u16* va = vst + lr * 64;
        bf16x8 fa0 = *(const bf16x8*)(va + ((lg ^ (lr & 7)) << 3));
        bf16x8 fa1 = *(const bf16x8*)(va + (((lg + 4) ^ (lr & 7)) << 3));
        #pragma unroll
        for (int ht = 0; ht < 4; ++ht){
            f32x4 c4 = {};
            c4 = __builtin_amdgcn_mfma_f32_16x16x32_bf16(fa0, nb0[ht], c4, 0, 0, 0);
            c4 = __builtin_amdgcn_mfma_f32_16x16x32_bf16(fa1, nb1[ht], c4, 0, 0, 0);
            const int h = ht * 16 + lr, gp = h >> 3;
            #pragma unroll
            for (int r = 0; r < 4; ++r){
                const int rs = lg * 4 + r;
                fst[rs * 64 + ((gp ^ (rs & 7)) << 3) + (h & 7)] = f2us(c4[r] + f1b[ht]);
            }
        }

        // coalesced writeout, re-swizzled to global position g ^ (i&7)
        {
            const int row = l >> 2, g0 = (l & 3) * 2;
            const size_t off = (((size_t)(nc * 64 + 16 * w + row) * NJ + j) * NI + i) * HO;
            #pragma unroll
            for (int gg = g0; gg < g0 + 2; ++gg){
                uint4 qv = *(const uint4*)&vst[row * 64 + ((gg ^ (row & 7)) << 3)];
                *(uint4*)(votes + off + ((gg ^ isw) << 3)) = qv;
                uint4 qf = *(const uint4*)&fst[row * 64 + ((gg ^ (row & 7)) << 3)];
                *(uint4*)(fnv + off + ((gg ^ isw) << 3)) = qf;
            }
        }
    }
}

// ---------------- Kernel C: routing; 2 coop waves per (n,j) ----------------
// Coalesced LINEAR tile loads into LDS (tiles pre-swizzled by i&7 in global),
// then one-time row reads LDS->regs. No address-diverged global gathers.
__global__ __launch_bounds__(128) void k_route(
    const u16* __restrict__ votes, const u16* __restrict__ fnv,
    const float* __restrict__ bijg, const float* __restrict__ mask,
    const float* __restrict__ alphaW, const float* __restrict__ alphab,
    const u16* __restrict__ wAb, const float* __restrict__ fe2b,
    const u16* __restrict__ wBb, const float* __restrict__ fn2b,
    const u16* __restrict__ wCtb, const float* __restrict__ fe1b,
    const int* __restrict__ itersp, float* __restrict__ out)
{
    __shared__ u16 v_l[4096];    // 8 KB votes tile (swizzled layout)
    __shared__ u16 f_l[4096];    // 8 KB fnv tile
    __shared__ float s_aij[64], s_vj[64], s_g[64], s_w[64], s_u[64];
    __shared__ float s_part[2][64];
    __shared__ float s_scal;

    const int bid = blockIdx.x;
    const int n = bid >> 4;
    const int j = bid & 15;
    const int t = threadIdx.x;
    const int lane = t & 63;
    const int wv = t >> 6;
    const size_t base = ((size_t)n * NJ + j) * (size_t)(NI * HO);

    // coalesced tile copy: wave0 -> v_l (votes), wave1 -> f_l (fnv)
    {
        const uint4* src = (const uint4*)((wv ? fnv : votes) + base);
        uint4 tb[8];
        #pragma unroll
        for (int c = 0; c < 8; ++c) tb[c] = src[c * 64 + lane];
        u16* dst = wv ? f_l : v_l;
        #pragma unroll
        for (int c = 0; c < 8; ++c) *(uint4*)&dst[c * 512 + lane * 8] = tb[c];
    }
    const float mki  = mask[(size_t)n * NI + lane];
    const float atti = (mki == 0.f) ? -3.0e38f : 0.f;
    const float braw = bijg[((size_t)n * NJ + j) * NI + lane];

    // own-tile row -> regs (intra-wave; granule c at position c ^ (lane&7))
    uint4 dr[8];
    {
        const u16* my = wv ? f_l : v_l;
        #pragma unroll
        for (int c = 0; c < 8; ++c)
            dr[c] = *(const uint4*)&my[lane * 64 + ((c ^ (lane & 7)) << 3)];
    }

    if (wv == 0){   // softmax over i
        float s = braw * mki + atti;
        float mx = s;
        #pragma unroll
        for (int off = 32; off; off >>= 1) mx = fmaxf(mx, __shfl_xor(mx, off));
        float pe = __expf(s - mx);
        float sm = pe;
        #pragma unroll
        for (int off = 32; off; off >>= 1) sm += __shfl_xor(sm, off);
        s_aij[lane] = pe / sm;
    }
    __syncthreads();   // v_l visible to wave1, s_aij visible to all

    const int iters = itersp[0];
    for (int it = 0; it < iters; ++it){
        // nv[h=lane] = sum_i aij[i]*votes[i][h]  (i split across waves)
        {
            float part = 0.f;
            const int i0 = wv << 5;
            const int gsh = (lane >> 3) << 3;   // granule base (u16 units) pre-XOR
            #pragma unroll 8
            for (int ii = 0; ii < 32; ++ii){
                const int i2 = i0 + ii;
                const int idx = i2 * 64 + (gsh ^ ((i2 & 7) << 3)) + (lane & 7);
                part += s_aij[i2] * us2f(v_l[idx]);
            }
            s_part[wv][lane] = part;
        }
        __syncthreads();
        if (wv == 0){
            float nv = gelu_exact(s_part[0][lane] + s_part[1][lane]);
            if (it == 0){
                s_vj[lane] = nv;
            } else {
                float dv = nv * alphaW[lane];
                #pragma unroll
                for (int off = 32; off; off >>= 1) dv += __shfl_xor(dv, off);
                float alpha = sigm(dv + alphab[0]);
                s_vj[lane] = alpha * nv + (1.f - alpha) * s_vj[lane];
            }
        }
        __syncthreads();
        if (it == iters - 1) break;

        if (wv == 0){
            // g = fe2(vj); u = fe1W^T g; scal = fe1b . g
            float a = 0.f;
            const uint4* wr = (const uint4*)(wAb + lane * 64);
            #pragma unroll
            for (int c = 0; c < 8; ++c) a += dot8(wr[c], &s_vj[c * 8]);
            float g = a + fe2b[lane];
            s_g[lane] = g;

            float ua = 0.f;
            const uint4* wc = (const uint4*)(wCtb + lane * 64);
            #pragma unroll
            for (int c = 0; c < 8; ++c) ua += dot8(wc[c], &s_g[c * 8]);
            s_u[lane] = ua;
            float cv = fe1b[lane] * g;
            #pragma unroll
            for (int off = 32; off; off >>= 1) cv += __shfl_xor(cv, off);
            if (lane == 0) s_scal = cv;
        } else {
            // w = fn2(vj); M[i=lane] = -sum_h |fnv[i][h] - w[h]|  (dr = fnv row)
            float a = 0.f;
            const uint4* wr = (const uint4*)(wBb + lane * 64);
            #pragma unroll
            for (int c = 0; c < 8; ++c) a += dot8(wr[c], &s_vj[c * 8]);
            s_w[lane] = a + fn2b[lane];

            float m = 0.f;
            #pragma unroll
            for (int c = 0; c < 8; ++c){
                uint4 q = dr[c];
                const float* wp = &s_w[c * 8];
                m += fabsf(bflo(q.x) - wp[0]) + fabsf(bfhi(q.x) - wp[1])
                   + fabsf(bflo(q.y) - wp[2]) + fabsf(bfhi(q.y) - wp[3])
                   + fabsf(bflo(q.z) - wp[4]) + fabsf(bfhi(q.z) - wp[5])
                   + fabsf(bflo(q.w) - wp[6]) + fabsf(bfhi(q.w) - wp[7]);
            }
            s_part[1][lane] = -m;    // reuse s_part[1] as M
        }
        __syncthreads();

        if (wv == 0){
            float e = s_scal;
            #pragma unroll
            for (int c = 0; c < 8; ++c) e += dot8(dr[c], &s_u[c * 8]);
            s_aij[lane] = tanhf(e) * sigm(s_part[1][lane] * mki + atti);
        }
        __syncthreads();
    }

    if (wv == 0)
        out[((size_t)n * NJ + j) * HO + lane] = s_vj[lane];
}

extern "C" void kernel_launch(void* const* d_in, const int* in_sizes, int n_in,
                              void* d_out, int out_size, void* d_ws, size_t ws_size,
                              hipStream_t stream)
{
    (void)in_sizes; (void)n_in; (void)out_size; (void)ws_size;
    const float* x      = (const float*)d_in[0];
    const float* mask   = (const float*)d_in[1];
    const float* Wcap   = (const float*)d_in[2];
    const float* Bcap   = (const float*)d_in[3];
    const float* Wv     = (const float*)d_in[4];
    const float* Bv     = (const float*)d_in[5];
    const float* scoreW = (const float*)d_in[6];
    const float* scoreb = (const float*)d_in[7];
    const float* alphaW = (const float*)d_in[8];
    const float* alphab = (const float*)d_in[9];
    const float* fe1W   = (const float*)d_in[10];
    const float* fe1b   = (const float*)d_in[11];
    const float* fe2W   = (const float*)d_in[12];
    const float* fe2b   = (const float*)d_in[13];
    const float* fn1W   = (const float*)d_in[14];
    const float* fn1b   = (const float*)d_in[15];
    const float* fn2W   = (const float*)d_in[16];
    const float* fn2b   = (const float*)d_in[17];
    const int*   itersp = (const int*)d_in[18];
    float* out = (float*)d_out;

    char* ws = (char*)d_ws;
    u16*   xcb   = (u16*)ws;                      //   4,194,304 B
    u16*   vts   = (u16*)(ws + 4194304);          //  67,108,864 B
    u16*   fnvp  = (u16*)(ws + 71303168);         //  67,108,864 B
    float* bij   = (float*)(ws + 138412032);      //   2,097,152 B
    u16*   fn1wb = (u16*)(ws + 140509184);        //       8,192 B
    u16*   wAb   = (u16*)(ws + 140517376);        //       8,192 B
    u16*   wBb   = (u16*)(ws + 140525568);        //       8,192 B
    u16*   wCtb  = (u16*)(ws + 140533760);        //       8,192 B  (~140.5 MB)

    k_prep_small<<<1, 256, 0, stream>>>(fn1W, fe2W, fn2W, fe1W, fn1wb, wAb, wBb, wCtb);
    k_xc        <<<512, 256, 0, stream>>>(x, Wcap, Bcap, xcb);
    k_votes     <<<dim3(64, 16), 256, 0, stream>>>(xcb, Wv, Bv, mask, fn1wb, fn1b,
                                                   scoreW, scoreb, vts, fnvp, bij);
    k_route     <<<8192, 128, 0, stream>>>(vts, fnvp, bij, mask, alphaW, alphab,
                                           wAb, fe2b, wBb, fn2b, wCtb, fe1b,
                                           itersp, out);
}

// Round 6
// 178.140 us; speedup vs baseline: 1.5151x; 1.0396x over previous
//
#include <hip/hip_runtime.h>
#include <hip/hip_bf16.h>

#define NN 512
#define NI 64
#define NJ 16
#define DD 256
#define HI 64
#define HO 64

typedef unsigned int  u32;
typedef unsigned short u16;

typedef __attribute__((ext_vector_type(8))) short bf16x8;
typedef __attribute__((ext_vector_type(4))) float f32x4;

__device__ __forceinline__ float gelu_exact(float x){
    return 0.5f * x * (1.0f + erff(x * 0.7071067811865476f));
}
__device__ __forceinline__ float sigm(float x){
    return 1.0f / (1.0f + __expf(-x));
}
__device__ __forceinline__ float us2f(u16 u){
    union { u32 ui; float f; } cv; cv.ui = ((u32)u) << 16; return cv.f;
}
__device__ __forceinline__ float bflo(u32 x){
    union { u32 u; float f; } c; c.u = x << 16; return c.f;
}
__device__ __forceinline__ float bfhi(u32 x){
    union { u32 u; float f; } c; c.u = x & 0xffff0000u; return c.f;
}
__device__ __forceinline__ u16 f2us(float f){
    union { float f; u32 u; } cv; cv.f = f;
    u32 r = cv.u + 0x7FFFu + ((cv.u >> 16) & 1u);   // RNE
    return (u16)(r >> 16);
}
__device__ __forceinline__ float dot8(uint4 q, const float* v){
    return bflo(q.x) * v[0] + bfhi(q.x) * v[1]
         + bflo(q.y) * v[2] + bfhi(q.y) * v[3]
         + bflo(q.z) * v[4] + bfhi(q.z) * v[5]
         + bflo(q.w) * v[6] + bfhi(q.w) * v[7];
}

// ------------- prep: small weights -> bf16 (fe1W transposed) -------------
__global__ __launch_bounds__(256) void k_prep_small(
    const float* __restrict__ fn1W, const float* __restrict__ fe2W,
    const float* __restrict__ fn2W, const float* __restrict__ fe1W,
    u16* __restrict__ fn1wb, u16* __restrict__ wAb,
    u16* __restrict__ wBb, u16* __restrict__ wCtb)
{
    const int t = threadIdx.x;
    #pragma unroll
    for (int u = 0; u < 16; ++u){
        int idx = t + u * 256;
        fn1wb[idx] = f2us(fn1W[idx]);
        wAb[idx]   = f2us(fe2W[idx]);
        wBb[idx]   = f2us(fn2W[idx]);
        int n = idx >> 6, h = idx & 63;
        wCtb[idx]  = f2us(fe1W[h * 64 + n]);   // wCt[n][h] = fe1W[h][n]
    }
}

// ---------------- Kernel A: xc = gelu(x @ Wcap + Bcap), bf16 out ----------------
__global__ __launch_bounds__(256) void k_xc(const float* __restrict__ x,
    const float* __restrict__ Wcap, const float* __restrict__ Bcap,
    u16* __restrict__ xcb)
{
    __shared__ float a_l[64][65];
    __shared__ float b_l[64][68];
    const int id = blockIdx.x;
    const int i  = ((id & 7) << 3) | (id >> 6);   // id%8 = i>>3 -> XCD
    const int nc = (id >> 3) & 7;
    const int n0 = nc * 64;
    const int t  = threadIdx.x;
    const int tr = t >> 4, tc = t & 15;
    float acc[4][4] = {};
    for (int k0 = 0; k0 < DD; k0 += 64){
        #pragma unroll
        for (int u = 0; u < 16; ++u){
            int idx = t + u * 256;
            int r = idx >> 6, c = idx & 63;
            a_l[r][c] = x[(size_t)(n0 + r) * (NI * DD) + (size_t)i * DD + k0 + c];
            b_l[r][c] = Wcap[(size_t)i * (DD * HI) + (size_t)(k0 + r) * HI + c];
        }
        __syncthreads();
        #pragma unroll 8
        for (int k = 0; k < 64; ++k){
            float av[4];
            #pragma unroll
            for (int q = 0; q < 4; ++q) av[q] = a_l[tr * 4 + q][k];
            float4 bv = *(const float4*)&b_l[k][tc * 4];
            #pragma unroll
            for (int q = 0; q < 4; ++q){
                acc[q][0] += av[q] * bv.x; acc[q][1] += av[q] * bv.y;
                acc[q][2] += av[q] * bv.z; acc[q][3] += av[q] * bv.w;
            }
        }
        __syncthreads();
    }
    #pragma unroll
    for (int q = 0; q < 4; ++q){
        int n = n0 + tr * 4 + q;
        float vv[4];
        #pragma unroll
        for (int p = 0; p < 4; ++p)
            vv[p] = gelu_exact(acc[q][p] + Bcap[i * HI + tc * 4 + p]);
        u32 p0 = (u32)f2us(vv[0]) | ((u32)f2us(vv[1]) << 16);
        u32 p1 = (u32)f2us(vv[2]) | ((u32)f2us(vv[3]) << 16);
        *(uint2*)&xcb[((size_t)n * NI + i) * HI + tc * 4] = make_uint2(p0, p1);
    }
}

// ------- Kernel B: one block per (i,j); votes + fn_v (MFMA) + bij -------
// (unchanged from round 5; tiles stored pre-swizzled by i&7 at 16-B granules)
__global__ __launch_bounds__(256) void k_votes(
    const u16* __restrict__ xcb, const float* __restrict__ Wv,
    const float* __restrict__ Bv, const float* __restrict__ mask,
    const u16* __restrict__ fn1wb, const float* __restrict__ fn1b,
    const float* __restrict__ scoreW, const float* __restrict__ scoreb,
    u16* __restrict__ votes, u16* __restrict__ fnv, float* __restrict__ bij)
{
    __shared__ u16 vstrip[4][1024];
    __shared__ u16 fstrip[4][1024];
    const int i = blockIdx.x, j = blockIdx.y;
    const int t = threadIdx.x, w = t >> 6, l = t & 63;
    const int lr = l & 15, lg = l >> 4;
    const int isw = i & 7;

    bf16x8 wb0[4], wb1[4], nb0[4], nb1[4];
    const float* wvp = Wv + (size_t)(i * NJ + j) * 4096;
    float bv[4], f1b[4], swv[4];
    #pragma unroll
    for (int ht = 0; ht < 4; ++ht){
        const int h = ht * 16 + lr;
        #pragma unroll
        for (int e = 0; e < 8; ++e){
            wb0[ht][e] = (short)f2us(wvp[(lg * 8 + e) * 64 + h]);
            wb1[ht][e] = (short)f2us(wvp[(32 + lg * 8 + e) * 64 + h]);
        }
        const u16* q = fn1wb + h * 64 + lg * 8;
        nb0[ht] = *(const bf16x8*)q;
        nb1[ht] = *(const bf16x8*)(q + 32);
        bv[ht]  = Bv[(size_t)(i * NJ + j) * HO + h];
        f1b[ht] = fn1b[h];
        swv[ht] = scoreW[h];
    }
    const float sb = scoreb[0];
    u16* vst = vstrip[w];
    u16* fst = fstrip[w];

    for (int nc = 0; nc < 8; ++nc){
        const int n0 = nc * 64 + 16 * w;
        const u16* ar = xcb + ((size_t)(n0 + lr) * NI + i) * HI + lg * 8;
        bf16x8 a0 = *(const bf16x8*)ar;
        bf16x8 a1 = *(const bf16x8*)(ar + 32);
        float mk[4];
        #pragma unroll
        for (int r = 0; r < 4; ++r)
            mk[r] = mask[(size_t)(n0 + lg * 4 + r) * NI + i];

        float p[4] = {};
        #pragma unroll
        for (int ht = 0; ht < 4; ++ht){
            f32x4 c4 = {};
            c4 = __builtin_amdgcn_mfma_f32_16x16x32_bf16(a0, wb0[ht], c4, 0, 0, 0);
            c4 = __builtin_amdgcn_mfma_f32_16x16x32_bf16(a1, wb1[ht], c4, 0, 0, 0);
            const int h = ht * 16 + lr, gp = h >> 3;
            #pragma unroll
            for (int r = 0; r < 4; ++r){
                const int rs = lg * 4 + r;
                float val = (c4[r] + bv[ht]) * mk[r];
                p[r] += val * swv[ht];
                vst[rs * 64 + ((gp ^ (rs & 7)) << 3) + (h & 7)] = f2us(val);
            }
        }
        #pragma unroll
        for (int r = 0; r < 4; ++r){
            float s = p[r];
            s += __shfl_xor(s, 1); s += __shfl_xor(s, 2);
            s += __shfl_xor(s, 4); s += __shfl_xor(s, 8);
            if (lr == 0)
                bij[((size_t)(n0 + lg * 4 + r) * NJ + j) * NI + i] = s + sb;
        }

        const u16* va = vst + lr * 64;
        bf16x8 fa0 = *(const bf16x8*)(va + ((lg ^ (lr & 7)) << 3));
        bf16x8 fa1 = *(const bf16x8*)(va + (((lg + 4) ^ (lr & 7)) << 3));
        #pragma unroll
        for (int ht = 0; ht < 4; ++ht){
            f32x4 c4 = {};
            c4 = __builtin_amdgcn_mfma_f32_16x16x32_bf16(fa0, nb0[ht], c4, 0, 0, 0);
            c4 = __builtin_amdgcn_mfma_f32_16x16x32_bf16(fa1, nb1[ht], c4, 0, 0, 0);
            const int h = ht * 16 + lr, gp = h >> 3;
            #pragma unroll
            for (int r = 0; r < 4; ++r){
                const int rs = lg * 4 + r;
                fst[rs * 64 + ((gp ^ (rs & 7)) << 3) + (h & 7)] = f2us(c4[r] + f1b[ht]);
            }
        }

        {
            const int row = l >> 2, g0 = (l & 3) * 2;
            const size_t off = (((size_t)(nc * 64 + 16 * w + row) * NJ + j) * NI + i) * HO;
            #pragma unroll
            for (int gg = g0; gg < g0 + 2; ++gg){
                uint4 qv = *(const uint4*)&vst[row * 64 + ((gg ^ (row & 7)) << 3)];
                *(uint4*)(votes + off + ((gg ^ isw) << 3)) = qv;
                uint4 qf = *(const uint4*)&fst[row * 64 + ((gg ^ (row & 7)) << 3)];
                *(uint4*)(fnv + off + ((gg ^ isw) << 3)) = qf;
            }
        }
    }
}

// ---------------- Kernel C: routing; ONE wave per (n,j), ZERO barriers ----------------
// Coalesced linear tile loads; fnv staged through the same 8 KB LDS as votes
// (fnv -> LDS -> dr_f regs, then votes overwrites; intra-wave lgkmcnt ordering).
// All cross-lane exchange via per-wave LDS arrays (same-wave, no barrier).
__global__ __launch_bounds__(256) void k_route(
    const u16* __restrict__ votes, const u16* __restrict__ fnv,
    const float* __restrict__ bijg, const float* __restrict__ mask,
    const float* __restrict__ alphaW, const float* __restrict__ alphab,
    const u16* __restrict__ wAb, const float* __restrict__ fe2b,
    const u16* __restrict__ wBb, const float* __restrict__ fn2b,
    const u16* __restrict__ wCtb, const float* __restrict__ fe1b,
    const int* __restrict__ itersp, float* __restrict__ out)
{
    __shared__ u16  t_l[4][4096];                  // 8 KB tile per wave
    __shared__ float s_aij[4][64], s_vj[4][64], s_g[4][64], s_w[4][64], s_u[4][64];

    const int t = threadIdx.x;
    const int wid = t >> 6;
    const int l = t & 63;
    const int pair = blockIdx.x * 4 + wid;
    const int n = pair >> 4, j = pair & 15;
    const size_t base = ((size_t)n * NJ + j) * (size_t)(NI * HO);

    u16*   tile = t_l[wid];
    float* aij  = s_aij[wid];
    float* svj  = s_vj[wid];
    float* sg   = s_g[wid];
    float* sw_  = s_w[wid];
    float* su   = s_u[wid];

    // ---- fnv -> LDS -> dr_f (row regs) ----
    uint4 dr_f[8];
    {
        const uint4* src = (const uint4*)(fnv + base);
        uint4 tb[8];
        #pragma unroll
        for (int c = 0; c < 8; ++c) tb[c] = src[c * 64 + l];
        #pragma unroll
        for (int c = 0; c < 8; ++c) *(uint4*)&tile[(c * 64 + l) * 8] = tb[c];
        #pragma unroll
        for (int c = 0; c < 8; ++c)
            dr_f[c] = *(const uint4*)&tile[l * 64 + ((c ^ (l & 7)) << 3)];
    }
    // ---- votes -> LDS (resident for nv loop + E-phase row reads) ----
    {
        const uint4* src = (const uint4*)(votes + base);
        uint4 tb[8];
        #pragma unroll
        for (int c = 0; c < 8; ++c) tb[c] = src[c * 64 + l];
        #pragma unroll
        for (int c = 0; c < 8; ++c) *(uint4*)&tile[(c * 64 + l) * 8] = tb[c];
    }

    const float mki  = mask[(size_t)n * NI + l];
    const float atti = (mki == 0.f) ? -3.0e38f : 0.f;

    {   // softmax over i (in-wave)
        float s = bijg[((size_t)n * NJ + j) * NI + l] * mki + atti;
        float mx = s;
        #pragma unroll
        for (int off = 32; off; off >>= 1) mx = fmaxf(mx, __shfl_xor(mx, off));
        float pe = __expf(s - mx);
        float sm = pe;
        #pragma unroll
        for (int off = 32; off; off >>= 1) sm += __shfl_xor(sm, off);
        aij[l] = pe / sm;
    }

    const int iters = itersp[0];
    float vj = 0.f;                                // lane l owns vj[h=l]
    for (int it = 0; it < iters; ++it){
        // nv[h=l] = sum_i aij[i]*votes[i][h]  (column reads, conflict-free)
        float acc = 0.f;
        const int gsh = (l >> 3) << 3;
        #pragma unroll 8
        for (int i2 = 0; i2 < 64; ++i2){
            const int idx = i2 * 64 + (gsh ^ ((i2 & 7) << 3)) + (l & 7);
            acc += aij[i2] * us2f(tile[idx]);
        }
        float nv = gelu_exact(acc);
        if (it == 0) vj = nv;
        else {
            float dv = nv * alphaW[l];
            #pragma unroll
            for (int off = 32; off; off >>= 1) dv += __shfl_xor(dv, off);
            float alpha = sigm(dv + alphab[0]);
            vj = alpha * nv + (1.f - alpha) * vj;
        }
        if (it == iters - 1) break;
        svj[l] = vj;

        // g = fe2(vj), w = fn2(vj)  (independent load chains, overlap)
        const uint4* wa = (const uint4*)(wAb + l * 64);
        const uint4* wb = (const uint4*)(wBb + l * 64);
        float ga = 0.f, wacc = 0.f;
        #pragma unroll
        for (int c = 0; c < 8; ++c){
            ga   += dot8(wa[c], &svj[c * 8]);
            wacc += dot8(wb[c], &svj[c * 8]);
        }
        float g = ga + fe2b[l];
        sg[l]  = g;
        sw_[l] = wacc + fn2b[l];

        // u = fe1W^T g ; scal = fe1b . g (broadcast via xor-reduce)
        const uint4* wc = (const uint4*)(wCtb + l * 64);
        float ua = 0.f;
        #pragma unroll
        for (int c = 0; c < 8; ++c) ua += dot8(wc[c], &sg[c * 8]);
        su[l] = ua;
        float cv = fe1b[l] * g;
        #pragma unroll
        for (int off = 32; off; off >>= 1) cv += __shfl_xor(cv, off);

        // M[i=l] = -sum_h |fnv[i][h] - w[h]|   (dr_f regs + s_w)
        float m = 0.f;
        #pragma unroll
        for (int c = 0; c < 8; ++c){
            uint4 q = dr_f[c];
            const float* wp = &sw_[c * 8];
            m += fabsf(bflo(q.x) - wp[0]) + fabsf(bfhi(q.x) - wp[1])
               + fabsf(bflo(q.y) - wp[2]) + fabsf(bfhi(q.y) - wp[3])
               + fabsf(bflo(q.z) - wp[4]) + fabsf(bfhi(q.z) - wp[5])
               + fabsf(bflo(q.w) - wp[6]) + fabsf(bfhi(q.w) - wp[7]);
        }

        // E[i=l] = votes[i].u + scal   (row reads from LDS)
        float e = cv;
        #pragma unroll
        for (int c = 0; c < 8; ++c){
            uint4 q = *(const uint4*)&tile[l * 64 + ((c ^ (l & 7)) << 3)];
            e += dot8(q, &su[c * 8]);
        }
        aij[l] = tanhf(e) * sigm(-m * mki + atti);
    }

    out[((size_t)n * NJ + j) * HO + l] = vj;
}

extern "C" void kernel_launch(void* const* d_in, const int* in_sizes, int n_in,
                              void* d_out, int out_size, void* d_ws, size_t ws_size,
                              hipStream_t stream)
{
    (void)in_sizes; (void)n_in; (void)out_size; (void)ws_size;
    const float* x      = (const float*)d_in[0];
    const float* mask   = (const float*)d_in[1];
    const float* Wcap   = (const float*)d_in[2];
    const float* Bcap   = (const float*)d_in[3];
    const float* Wv     = (const float*)d_in[4];
    const float* Bv     = (const float*)d_in[5];
    const float* scoreW = (const float*)d_in[6];
    const float* scoreb = (const float*)d_in[7];
    const float* alphaW = (const float*)d_in[8];
    const float* alphab = (const float*)d_in[9];
    const float* fe1W   = (const float*)d_in[10];
    const float* fe1b   = (const float*)d_in[11];
    const float* fe2W   = (const float*)d_in[12];
    const float* fe2b   = (const float*)d_in[13];
    const float* fn1W   = (const float*)d_in[14];
    const float* fn1b   = (const float*)d_in[15];
    const float* fn2W   = (const float*)d_in[16];
    const float* fn2b   = (const float*)d_in[17];
    const int*   itersp = (const int*)d_in[18];
    float* out = (float*)d_out;

    char* ws = (char*)d_ws;
    u16*   xcb   = (u16*)ws;                      //   4,194,304 B
    u16*   vts   = (u16*)(ws + 4194304);          //  67,108,864 B
    u16*   fnvp  = (u16*)(ws + 71303168);         //  67,108,864 B
    float* bij   = (float*)(ws + 138412032);      //   2,097,152 B
    u16*   fn1wb = (u16*)(ws + 140509184);        //       8,192 B
    u16*   wAb   = (u16*)(ws + 140517376);        //       8,192 B
    u16*   wBb   = (u16*)(ws + 140525568);        //       8,192 B
    u16*   wCtb  = (u16*)(ws + 140533760);        //       8,192 B  (~140.5 MB)

    k_prep_small<<<1, 256, 0, stream>>>(fn1W, fe2W, fn2W, fe1W, fn1wb, wAb, wBb, wCtb);
    k_xc        <<<512, 256, 0, stream>>>(x, Wcap, Bcap, xcb);
    k_votes     <<<dim3(64, 16), 256, 0, stream>>>(xcb, Wv, Bv, mask, fn1wb, fn1b,
                                                   scoreW, scoreb, vts, fnvp, bij);
    k_route     <<<2048, 256, 0, stream>>>(vts, fnvp, bij, mask, alphaW, alphab,
                                           wAb, fe2b, wBb, fn2b, wCtb, fe1b,
                                           itersp, out);
}